// Round 4
// baseline (452.838 us; speedup 1.0000x reference)
//
#include <hip/hip_runtime.h>
#include <hip/hip_bf16.h>

// Sizes (fixed by the problem)
#define HDIM 512
#define BB 32
#define SS 4096
#define BS 64                 // rows per chunk
#define CPB 8                 // chunks per block
#define NBPB (SS/(BS*CPB))    // 8 blocks per b
#define NBLK (BB*NBPB)        // 256 blocks = 1/CU

typedef __attribute__((ext_vector_type(8))) short short8;   // 8 x bf16
typedef __attribute__((ext_vector_type(4))) float f32x4;

// Workspace layout (bytes)
#define WS_QB   0                         // 32*512*4   = 65536
#define WS_WRB  65536                     // 512*512*2  = 524288
#define WS_PM   (65536+524288)            // 256*4 (8KB region)
#define WS_PD   (WS_PM+8192)              // 256*4 (8KB region)
#define WS_PU   (WS_PD+8192)              // 256*512*4 = 512KB

__device__ __forceinline__ unsigned short f2bf(float f){
  unsigned u = __float_as_uint(f);
  u += 0x7FFFu + ((u >> 16) & 1u);        // RNE
  return (unsigned short)(u >> 16);
}

__device__ __forceinline__ float fast_tanh(float x){
  float e = __expf(2.f * x);
  return 1.f - __fdividef(2.f, 1.f + e);
}

// ---------------- K1: prep (fused) ----------------
__global__ __launch_bounds__(256) void k_prep(const float* __restrict__ Wr,
                                              unsigned short* __restrict__ wrb,
                                              const float* __restrict__ query,
                                              const float* __restrict__ Wq,
                                              const float* __restrict__ bq,
                                              const float* __restrict__ br,
                                              float* __restrict__ qb){
  __shared__ __align__(16) float sq[HDIM];
  int t = threadIdx.x;
  if (blockIdx.x < 256){
    int idx = blockIdx.x*256 + t;
    f32x4 v = ((const f32x4*)Wr)[idx];
    ushort4 o;
    o.x = f2bf(v.x); o.y = f2bf(v.y); o.z = f2bf(v.z); o.w = f2bf(v.w);
    ((ushort4*)wrb)[idx] = o;
  } else {
    int b = blockIdx.x - 256;
    sq[t] = query[b*HDIM + t];
    sq[t+256] = query[b*HDIM + t + 256];
    __syncthreads();
    const f32x4* sq4 = (const f32x4*)sq;
    for (int hh = 0; hh < 2; ++hh){
      int h = t + hh*256;
      const f32x4* w4 = (const f32x4*)(Wq + (size_t)h*HDIM);
      float acc = bq[h] + br[h];
      #pragma unroll 4
      for (int k = 0; k < HDIM/4; ++k){
        f32x4 w = w4[k]; f32x4 q = sq4[k];
        acc += w.x*q.x + w.y*q.y + w.z*q.z + w.w*q.w;
      }
      qb[b*HDIM + h] = acc;
    }
  }
}

// ---------------- K2: main fused kernel ----------------
// 256 blocks (1/CU) x 512 threads. Block owns 512 s-rows = 8 chunks of 64.
// LDS double-buffer: GEMM+epi+u on buf[c&1] while chunk c+1's 128KB stream
// (issued at iteration top, 16 f32x4/thread) is in flight; cvt+ds_write to
// buf[(c+1)&1] at iteration end. Barriers never drain fresh loads.
__global__ __launch_bounds__(512, 2) void k_main(const float* __restrict__ ref,
                                                 const unsigned short* __restrict__ wrb,
                                                 const float* __restrict__ qb,
                                                 const float* __restrict__ V,
                                                 float* __restrict__ pm,
                                                 float* __restrict__ pd,
                                                 float* __restrict__ pu){
  int bid = blockIdx.x;
  int b = bid >> 3;                 // 8 blocks per b
  int grp = bid & 7;
  int tid = threadIdx.x;
  int w = tid >> 6, lane = tid & 63;
  int lo16 = lane & 15, g = lane >> 4;

  __shared__ __align__(16) unsigned short sA[2][BS*HDIM]; // 2 x 64KB swizzled
  __shared__ __align__(16) float sQb[HDIM];
  __shared__ __align__(16) float sV[HDIM];
  __shared__ float sLog[8][BS];
  __shared__ float sE[BS];
  __shared__ float sMD[2];

  sQb[tid] = qb[b*HDIM + tid];     // 512 threads == HDIM
  sV[tid]  = V[tid];

  const f32x4* refb4 = (const f32x4*)(ref + ((size_t)b*SS + (size_t)grp*(BS*CPB))*HDIM);

  f32x4 P[16];   // 64 VGPR prefetch: one 64x512-f32 chunk, 16 f32x4/thread

  // ---- prologue: stage chunk 0, then put chunk 1 in flight ----
  {
    const f32x4* s = refb4 + tid;
    #pragma unroll
    for (int i = 0; i < 16; ++i) P[i] = s[512*i];
    #pragma unroll
    for (int i = 0; i < 16; ++i){
      int idx = tid + 512*i;
      int row = idx >> 7, c4 = idx & 127;
      f32x4 v = P[i];
      ushort4 o;
      o.x = f2bf(v.x); o.y = f2bf(v.y); o.z = f2bf(v.z); o.w = f2bf(v.w);
      unsigned byte = ((unsigned)(row*1024 + c4*8)) ^ ((unsigned)(row & 7) << 4);
      *(ushort4*)((char*)sA[0] + byte) = o;
    }
  }
  __syncthreads();
  {
    const f32x4* s = refb4 + (size_t)1*(BS*HDIM/4) + tid;
    #pragma unroll
    for (int i = 0; i < 16; ++i) P[i] = s[512*i];
  }

  float m_run = -3.0e38f, d_run = 0.f, u_run = 0.f;

  for (int c = 0; c < CPB; ++c){
    unsigned short* cur = sA[c & 1];
    unsigned short* nxt = sA[(c+1) & 1];

    // issue prefetch for chunk c+1 (consumed by writeP at this iter's end).
    // c==0: chunk 1 already in flight from prologue.
    if (c >= 1 && c + 1 < CPB){
      const f32x4* s = refb4 + (size_t)(c+1)*(BS*HDIM/4) + tid;
      #pragma unroll
      for (int i = 0; i < 16; ++i) P[i] = s[512*i];
    }

    // ---- GEMM: this wave covers cols [w*64, w*64+64), rows 0..63 ----
    f32x4 acc[4][4];
    #pragma unroll
    for (int m = 0; m < 4; ++m)
      #pragma unroll
      for (int n = 0; n < 4; ++n)
        acc[m][n] = (f32x4){0.f, 0.f, 0.f, 0.f};

    {
      const unsigned short* wb = wrb + (size_t)(w*64 + lo16)*HDIM + g*8;
      short8 bf0[4], bf1[4];
      #pragma unroll
      for (int n = 0; n < 4; ++n)
        bf0[n] = *(const short8*)(wb + n*16*HDIM);

      #pragma unroll
      for (int kt = 0; kt < 16; kt += 2){
        // prefetch kt+1's B-frags
        #pragma unroll
        for (int n = 0; n < 4; ++n)
          bf1[n] = *(const short8*)(wb + n*16*HDIM + (kt+1)*32);
        short8 af[4];
        #pragma unroll
        for (int m = 0; m < 4; ++m){
          int row = 16*m + lo16;
          unsigned byte = ((unsigned)(row*1024 + kt*64 + g*16)) ^ ((unsigned)(row & 7) << 4);
          af[m] = *(const short8*)((const char*)cur + byte);
        }
        #pragma unroll
        for (int m = 0; m < 4; ++m)
          #pragma unroll
          for (int n = 0; n < 4; ++n)
            acc[m][n] = __builtin_amdgcn_mfma_f32_16x16x32_bf16(af[m], bf0[n], acc[m][n], 0, 0, 0);

        // prefetch kt+2's B-frags
        if (kt + 2 < 16){
          #pragma unroll
          for (int n = 0; n < 4; ++n)
            bf0[n] = *(const short8*)(wb + n*16*HDIM + (kt+2)*32);
        }
        #pragma unroll
        for (int m = 0; m < 4; ++m){
          int row = 16*m + lo16;
          unsigned byte = ((unsigned)(row*1024 + (kt+1)*64 + g*16)) ^ ((unsigned)(row & 7) << 4);
          af[m] = *(const short8*)((const char*)cur + byte);
        }
        #pragma unroll
        for (int m = 0; m < 4; ++m)
          #pragma unroll
          for (int n = 0; n < 4; ++n)
            acc[m][n] = __builtin_amdgcn_mfma_f32_16x16x32_bf16(af[m], bf1[n], acc[m][n], 0, 0, 0);
      }
    }

    // ---- epilogue: D-layout col=lane&15 (+n*16+w*64), row=16m+4g+r ----
    float lacc[4][4];
    #pragma unroll
    for (int m = 0; m < 4; ++m)
      #pragma unroll
      for (int r = 0; r < 4; ++r)
        lacc[m][r] = 0.f;
    #pragma unroll
    for (int n = 0; n < 4; ++n){
      int col = w*64 + n*16 + lo16;
      float qv = sQb[col], vv = sV[col];
      #pragma unroll
      for (int m = 0; m < 4; ++m)
        #pragma unroll
        for (int r = 0; r < 4; ++r){
          float x = qv + acc[m][n][r];
          lacc[m][r] += vv * fast_tanh(x);
        }
    }
    #pragma unroll
    for (int m = 0; m < 4; ++m)
      #pragma unroll
      for (int r = 0; r < 4; ++r){
        float v = lacc[m][r];
        v += __shfl_xor(v, 1); v += __shfl_xor(v, 2);
        v += __shfl_xor(v, 4); v += __shfl_xor(v, 8);
        lacc[m][r] = v;
      }
    if (lo16 == 0){
      #pragma unroll
      for (int m = 0; m < 4; ++m)
        #pragma unroll
        for (int r = 0; r < 4; ++r)
          sLog[w][16*m + 4*g + r] = lacc[m][r];
    }
    __syncthreads();

    // ---- chunk softmax partials (wave 0; 64 lanes = 64 rows) ----
    if (w == 0){
      float l = sLog[0][lane] + sLog[1][lane] + sLog[2][lane] + sLog[3][lane]
              + sLog[4][lane] + sLog[5][lane] + sLog[6][lane] + sLog[7][lane];
      float mx = l;
      mx = fmaxf(mx, __shfl_xor(mx, 1));  mx = fmaxf(mx, __shfl_xor(mx, 2));
      mx = fmaxf(mx, __shfl_xor(mx, 4));  mx = fmaxf(mx, __shfl_xor(mx, 8));
      mx = fmaxf(mx, __shfl_xor(mx, 16)); mx = fmaxf(mx, __shfl_xor(mx, 32));
      float e = __expf(l - mx);
      float d = e;
      d += __shfl_xor(d, 1); d += __shfl_xor(d, 2); d += __shfl_xor(d, 4);
      d += __shfl_xor(d, 8); d += __shfl_xor(d, 16); d += __shfl_xor(d, 32);
      sE[lane] = e;
      if (lane == 0){ sMD[0] = mx; sMD[1] = d; }
    }
    __syncthreads();

    // ---- u[k]: k = tid (one col per thread), sum over 64 rows ----
    float u0 = 0.f;
    #pragma unroll 8
    for (int s = 0; s < BS; ++s){
      unsigned byte = ((unsigned)(s*1024 + tid*2)) ^ ((unsigned)(s & 7) << 4);
      unsigned short us = *(const unsigned short*)((const char*)cur + byte);
      u0 += sE[s] * __uint_as_float(((unsigned)us) << 16);
    }

    // ---- online merge ----
    float mt = sMD[0], dt = sMD[1];
    float mnew = fmaxf(m_run, mt);
    float so = __expf(m_run - mnew);
    float sn = __expf(mt - mnew);
    u_run = u_run*so + u0*sn;
    d_run = d_run*so + dt*sn;
    m_run = mnew;

    // ---- commit prefetched chunk c+1 into nxt buffer ----
    if (c + 1 < CPB){
      #pragma unroll
      for (int i = 0; i < 16; ++i){
        int idx = tid + 512*i;
        int row = idx >> 7, c4 = idx & 127;
        f32x4 v = P[i];
        ushort4 o;
        o.x = f2bf(v.x); o.y = f2bf(v.y); o.z = f2bf(v.z); o.w = f2bf(v.w);
        unsigned byte = ((unsigned)(row*1024 + c4*8)) ^ ((unsigned)(row & 7) << 4);
        *(ushort4*)((char*)nxt + byte) = o;
      }
      __syncthreads();   // nxt visible; nothing fresh in vmem queue here
    }
  }

  if (tid == 0){ pm[bid] = m_run; pd[bid] = d_run; }
  pu[(size_t)bid*HDIM + tid] = u_run;
}

// ---------------- K3: combine 8 partials per b + out = Wr @ u + br ----------------
__global__ __launch_bounds__(256) void k_final(const float* __restrict__ Wr,
                                               const float* __restrict__ br,
                                               const float* __restrict__ pm,
                                               const float* __restrict__ pd,
                                               const float* __restrict__ pu,
                                               float* __restrict__ out){
  int b = blockIdx.x, t = threadIdx.x, lane = t & 63, w = t >> 6;
  __shared__ float sSc[NBPB];
  __shared__ __align__(16) float sU[HDIM];
  __shared__ float sMD0;

  if (w == 0){
    float m = (lane < NBPB) ? pm[b*NBPB + lane] : -3.0e38f;
    float mx = m;
    mx = fmaxf(mx, __shfl_xor(mx, 1));  mx = fmaxf(mx, __shfl_xor(mx, 2));
    mx = fmaxf(mx, __shfl_xor(mx, 4));  mx = fmaxf(mx, __shfl_xor(mx, 8));
    mx = fmaxf(mx, __shfl_xor(mx, 16)); mx = fmaxf(mx, __shfl_xor(mx, 32));
    float sc = (lane < NBPB) ? __expf(m - mx) : 0.f;
    float d = sc * ((lane < NBPB) ? pd[b*NBPB + lane] : 0.f);
    d += __shfl_xor(d, 1); d += __shfl_xor(d, 2); d += __shfl_xor(d, 4);
    d += __shfl_xor(d, 8); d += __shfl_xor(d, 16); d += __shfl_xor(d, 32);
    if (lane < NBPB) sSc[lane] = sc;
    if (lane == 0) sMD0 = d;
  }
  __syncthreads();

  float inv = 1.f / sMD0;
  float u0 = 0.f, u1 = 0.f;
  #pragma unroll
  for (int c = 0; c < NBPB; ++c){
    float sc = sSc[c];
    const float* p = pu + ((size_t)(b*NBPB + c))*HDIM;
    u0 += sc * p[t];
    u1 += sc * p[t+256];
  }
  sU[t]     = u0 * inv;
  sU[t+256] = u1 * inv;
  __syncthreads();

  const f32x4* su4 = (const f32x4*)sU;
  for (int hh = 0; hh < 2; ++hh){
    int h = t + hh*256;
    const f32x4* w4 = (const f32x4*)(Wr + (size_t)h*HDIM);
    float acc = br[h];
    #pragma unroll 4
    for (int k = 0; k < HDIM/4; ++k){
      f32x4 wv = w4[k], uv = su4[k];
      acc += wv.x*uv.x + wv.y*uv.y + wv.z*uv.z + wv.w*uv.w;
    }
    out[b*HDIM + h] = acc;
  }
}

extern "C" void kernel_launch(void* const* d_in, const int* in_sizes, int n_in,
                              void* d_out, int out_size, void* d_ws, size_t ws_size,
                              hipStream_t stream){
  const float* query = (const float*)d_in[0];
  const float* ref   = (const float*)d_in[1];
  const float* Wq    = (const float*)d_in[2];
  const float* bq    = (const float*)d_in[3];
  const float* Wr    = (const float*)d_in[4];
  const float* br    = (const float*)d_in[5];
  const float* V     = (const float*)d_in[6];
  char* ws = (char*)d_ws;
  float*          qbv = (float*)(ws + WS_QB);
  unsigned short* wrb = (unsigned short*)(ws + WS_WRB);
  float*          pm  = (float*)(ws + WS_PM);
  float*          pd  = (float*)(ws + WS_PD);
  float*          pu  = (float*)(ws + WS_PU);
  float* out = (float*)d_out;

  k_prep<<<dim3(288), dim3(256), 0, stream>>>(Wr, wrb, query, Wq, bq, br, qbv);
  k_main<<<dim3(NBLK), dim3(512), 0, stream>>>(ref, wrb, qbv, V, pm, pd, pu);
  k_final<<<dim3(BB), dim3(256), 0, stream>>>(Wr, br, pm, pd, pu, out);
}

// Round 5
// 268.746 us; speedup vs baseline: 1.6850x; 1.6850x over previous
//
#include <hip/hip_runtime.h>
#include <hip/hip_bf16.h>

// Sizes (fixed by the problem)
#define HDIM 512
#define BB 32
#define SS 4096
#define ROWS_PER_BLOCK 512
#define NBPB 8                 // blocks per b
#define NBLK 256               // 1 block per CU
#define NT 8                   // 64-row tiles per block
#define NQ 32                  // quarters per block (NT*4), quarter = 64 rows x 128 K

typedef __attribute__((ext_vector_type(8))) short short8;   // 8 x bf16
typedef __attribute__((ext_vector_type(4))) float f32x4;

// Workspace layout (bytes)
#define WS_QB   0                         // 32*512*4   = 65536
#define WS_WRB  65536                     // 512*512*2  = 524288
#define WS_PM   (65536+524288)            // 256*4 (8KB region)
#define WS_PD   (WS_PM+8192)              // 256*4 (8KB region)
#define WS_PU   (WS_PD+8192)              // 256*512*4 = 512KB

__device__ __forceinline__ unsigned short f2bf(float f){
  unsigned u = __float_as_uint(f);
  u += 0x7FFFu + ((u >> 16) & 1u);        // RNE
  return (unsigned short)(u >> 16);
}

__device__ __forceinline__ float fast_tanh(float x){
  float e = __expf(2.f * x);
  return 1.f - __fdividef(2.f, 1.f + e);
}

// LDS-only barrier: waits LDS ops, leaves global_load_lds DMAs (vmcnt) in flight.
__device__ __forceinline__ void lds_barrier(){
  __builtin_amdgcn_sched_barrier(0);
  asm volatile("s_waitcnt lgkmcnt(0)" ::: "memory");
  __builtin_amdgcn_s_barrier();
  __builtin_amdgcn_sched_barrier(0);
}

__device__ __forceinline__ void wait_vm0(){
  asm volatile("s_waitcnt vmcnt(0)" ::: "memory");
  __builtin_amdgcn_sched_barrier(0);
}

// async DMA one 64x128-f32 quarter (32KB) into linear LDS buffer. No VGPR staging.
__device__ __forceinline__ void dma_quarter(const char* refBytes, int Q, float* fdst,
                                            int w, int lane, int bid){
  int T = Q >> 2, q = Q & 3;
  const char* gbase = refBytes + ((size_t)bid*ROWS_PER_BLOCK + (size_t)T*64)*2048 + q*512;
  char* lbase = (char*)fdst;
  #pragma unroll
  for (int j = 0; j < 2; ++j){
    int rr = 2*(j*16 + w) + (lane >> 5);
    const char* g = gbase + (size_t)rr*2048 + (size_t)(lane & 31)*16;
    char* l = lbase + (j*16 + w)*1024;   // wave-uniform base; HW adds lane*16
    __builtin_amdgcn_global_load_lds((const __attribute__((address_space(1))) void*)g,
                                     (__attribute__((address_space(3))) void*)l, 16, 0, 0);
  }
}

// convert one quarter: f32 linear LDS -> bf16 swizzled LDS. Each element once.
// bf16 layout: byte = row*256 + ((kslot ^ (row&15))*16) + (k&7)*2, kslot=k>>3
__device__ __forceinline__ void convert_quarter(const float* fsrc, unsigned short* bdst,
                                                int w, int lane){
  #pragma unroll
  for (int j = 0; j < 2; ++j){
    int off = (j*16 + w)*1024 + lane*16;
    f32x4 v = *(const f32x4*)((const char*)fsrc + off);
    int e0 = off >> 2;
    int row = e0 >> 7, k0 = e0 & 127;
    unsigned long long pk = (unsigned long long)f2bf(v.x)
                          | ((unsigned long long)f2bf(v.y) << 16)
                          | ((unsigned long long)f2bf(v.z) << 32)
                          | ((unsigned long long)f2bf(v.w) << 48);
    unsigned byte = (unsigned)(row*256 + (((k0 >> 3) ^ (row & 15))*16) + (k0 & 7)*2);
    *(unsigned long long*)((char*)bdst + byte) = pk;
  }
}

// ---------------- K1: prep (fused) ----------------
__global__ __launch_bounds__(256) void k_prep(const float* __restrict__ Wr,
                                              unsigned short* __restrict__ wrb,
                                              const float* __restrict__ query,
                                              const float* __restrict__ Wq,
                                              const float* __restrict__ bq,
                                              const float* __restrict__ br,
                                              float* __restrict__ qb){
  __shared__ __align__(16) float sq[HDIM];
  int t = threadIdx.x;
  if (blockIdx.x < 256){
    int idx = blockIdx.x*256 + t;
    f32x4 v = ((const f32x4*)Wr)[idx];
    ushort4 o;
    o.x = f2bf(v.x); o.y = f2bf(v.y); o.z = f2bf(v.z); o.w = f2bf(v.w);
    ((ushort4*)wrb)[idx] = o;
  } else {
    int b = blockIdx.x - 256;
    sq[t] = query[b*HDIM + t];
    sq[t+256] = query[b*HDIM + t + 256];
    __syncthreads();
    const f32x4* sq4 = (const f32x4*)sq;
    for (int hh = 0; hh < 2; ++hh){
      int h = t + hh*256;
      const f32x4* w4 = (const f32x4*)(Wq + (size_t)h*HDIM);
      float acc = bq[h] + br[h];
      #pragma unroll 4
      for (int k = 0; k < HDIM/4; ++k){
        f32x4 w = w4[k]; f32x4 q = sq4[k];
        acc += w.x*q.x + w.y*q.y + w.z*q.z + w.w*q.w;
      }
      qb[b*HDIM + h] = acc;
    }
  }
}

// ---------------- K2: main fused kernel ----------------
// 256 blocks x 1024 threads (16 waves), 1/CU. Block owns 512 rows = 8 tiles
// of 64; tile split into 4 K-quarters. Per quarter: DMA(Q+2) in flight under
// GEMM(Q); convert(Q+1) f32->bf16. bf16 5-ring keeps a full tile resident
// for the u-pass. All barriers lgkm-only so DMAs cross them.
__global__ __launch_bounds__(1024, 4) void k_main(const float* __restrict__ ref,
                                                  const unsigned short* __restrict__ wrb,
                                                  const float* __restrict__ qb,
                                                  const float* __restrict__ V,
                                                  float* __restrict__ pm,
                                                  float* __restrict__ pd,
                                                  float* __restrict__ pu){
  int bid = blockIdx.x;
  int b = bid >> 3;
  int tid = threadIdx.x;
  int w = tid >> 6, lane = tid & 63;
  int lo16 = lane & 15, g = lane >> 4;

  __shared__ __align__(16) float fbuf[2][64*128];            // 2 x 32KB f32 ring
  __shared__ __align__(16) unsigned short bQ[5][64*128];     // 5 x 16KB bf16 ring
  __shared__ __align__(16) float sQb[HDIM];
  __shared__ __align__(16) float sV[HDIM];
  __shared__ __align__(16) char sScratch[4096 + 256 + 16];   // sLog | sE | sMD (sU aliases sLog)
  float (*sLog)[64] = (float(*)[64])sScratch;
  float* sE  = (float*)(sScratch + 4096);
  float* sMD = (float*)(sScratch + 4096 + 256);
  float* sU  = (float*)sScratch;

  if (tid < HDIM){
    sQb[tid] = qb[b*HDIM + tid];
    sV[tid]  = V[tid];
  }

  const char* refB = (const char*)ref;

  // ---- prologue ----
  dma_quarter(refB, 0, fbuf[0], w, lane, bid);
  wait_vm0();
  lds_barrier();
  convert_quarter(fbuf[0], bQ[0], w, lane);
  dma_quarter(refB, 1, fbuf[1], w, lane, bid);

  float m_run = -3.0e38f, d_run = 0.f, u_run = 0.f;
  f32x4 acc[4][2];

  for (int Q = 0; Q < NQ; ++Q){
    int q = Q & 3;

    wait_vm0();        // DMA(Q+1) done (in flight since previous iteration)
    lds_barrier();     // cross-wave visibility: DMA + convert(Q) writes

    if (Q + 1 < NQ) convert_quarter(fbuf[(Q+1) & 1], bQ[(Q+1) % 5], w, lane);
    if (Q + 2 < NQ) dma_quarter(refB, Q+2, fbuf[(Q+2) & 1], w, lane, bid);

    // ---- GEMM quarter Q: wave covers cols [w*32, w*32+32), rows 0..63 ----
    if (q == 0){
      #pragma unroll
      for (int m = 0; m < 4; ++m)
        #pragma unroll
        for (int n = 0; n < 2; ++n)
          acc[m][n] = (f32x4){0.f, 0.f, 0.f, 0.f};
    }
    {
      const char* bb = (const char*)bQ[Q % 5];
      const unsigned short* wb = wrb + (size_t)(w*32 + lo16)*HDIM + g*8;
      #pragma unroll
      for (int kk = 0; kk < 4; ++kk){
        short8 af[4];
        #pragma unroll
        for (int m = 0; m < 4; ++m){
          int row = 16*m + lo16;
          unsigned byte = (unsigned)(row*256 + (((kk*4 + g) ^ lo16)*16));
          af[m] = *(const short8*)(bb + byte);
        }
        short8 bfr[2];
        #pragma unroll
        for (int n = 0; n < 2; ++n)
          bfr[n] = *(const short8*)(wb + (size_t)n*16*HDIM + (q*4 + kk)*32);
        #pragma unroll
        for (int m = 0; m < 4; ++m)
          #pragma unroll
          for (int n = 0; n < 2; ++n)
            acc[m][n] = __builtin_amdgcn_mfma_f32_16x16x32_bf16(af[m], bfr[n], acc[m][n], 0, 0, 0);
      }
    }

    if (q == 3){
      int T = Q >> 2;
      // ---- epilogue: D-layout col=lane&15 (+n*16+w*32), row=16m+4g+r ----
      float lacc[4][4];
      #pragma unroll
      for (int m = 0; m < 4; ++m)
        #pragma unroll
        for (int r = 0; r < 4; ++r)
          lacc[m][r] = 0.f;
      #pragma unroll
      for (int n = 0; n < 2; ++n){
        int col = w*32 + n*16 + lo16;
        float qv = sQb[col], vv = sV[col];
        #pragma unroll
        for (int m = 0; m < 4; ++m)
          #pragma unroll
          for (int r = 0; r < 4; ++r){
            float x = qv + acc[m][n][r];
            lacc[m][r] += vv * fast_tanh(x);
          }
      }
      #pragma unroll
      for (int m = 0; m < 4; ++m)
        #pragma unroll
        for (int r = 0; r < 4; ++r){
          float v = lacc[m][r];
          v += __shfl_xor(v, 1); v += __shfl_xor(v, 2);
          v += __shfl_xor(v, 4); v += __shfl_xor(v, 8);
          lacc[m][r] = v;
        }
      if (lo16 == 0){
        #pragma unroll
        for (int m = 0; m < 4; ++m)
          #pragma unroll
          for (int r = 0; r < 4; ++r)
            sLog[w][16*m + 4*g + r] = lacc[m][r];
      }
      lds_barrier();

      if (w == 0){
        float l = 0.f;
        #pragma unroll
        for (int ww = 0; ww < 16; ++ww) l += sLog[ww][lane];
        float mx = l;
        mx = fmaxf(mx, __shfl_xor(mx, 1));  mx = fmaxf(mx, __shfl_xor(mx, 2));
        mx = fmaxf(mx, __shfl_xor(mx, 4));  mx = fmaxf(mx, __shfl_xor(mx, 8));
        mx = fmaxf(mx, __shfl_xor(mx, 16)); mx = fmaxf(mx, __shfl_xor(mx, 32));
        float e = __expf(l - mx);
        float d = e;
        d += __shfl_xor(d, 1); d += __shfl_xor(d, 2); d += __shfl_xor(d, 4);
        d += __shfl_xor(d, 8); d += __shfl_xor(d, 16); d += __shfl_xor(d, 32);
        sE[lane] = e;
        if (lane == 0){ sMD[0] = mx; sMD[1] = d; }
      }
      lds_barrier();

      // ---- u-pass: col = tid&511, rows half (tid>>9), from bf16 ring ----
      {
        int cc = tid & 511, hh = tid >> 9;
        int qq = cc >> 7, k0 = cc & 127;
        const char* bb = (const char*)bQ[(4*T + qq) % 5];
        unsigned base = (unsigned)((((k0 >> 3)) * 16) + (k0 & 7)*2);
        float u0 = 0.f;
        #pragma unroll 8
        for (int s2 = 0; s2 < 32; ++s2){
          int s = hh*32 + s2;
          unsigned byte = (unsigned)(s*256) + (base ^ (unsigned)((s & 15) << 4));
          unsigned short us = *(const unsigned short*)(bb + byte);
          u0 += sE[s] * __uint_as_float(((unsigned)us) << 16);
        }
        float mt = sMD[0], dt = sMD[1];
        float mnew = fmaxf(m_run, mt);
        float so = __expf(m_run - mnew);
        float sn = __expf(mt - mnew);
        u_run = u_run*so + u0*sn;
        d_run = d_run*so + dt*sn;
        m_run = mnew;
      }
    }
    lds_barrier();
  }

  // ---- combine row-halves, write partials ----
  sU[tid] = u_run;
  lds_barrier();
  if (tid < HDIM)
    pu[(size_t)bid*HDIM + tid] = sU[tid] + sU[tid + 512];
  if (tid == 0){ pm[bid] = m_run; pd[bid] = d_run; }
}

// ---------------- K3: combine 8 partials per b + out = Wr @ u + br ----------------
__global__ __launch_bounds__(256) void k_final(const float* __restrict__ Wr,
                                               const float* __restrict__ br,
                                               const float* __restrict__ pm,
                                               const float* __restrict__ pd,
                                               const float* __restrict__ pu,
                                               float* __restrict__ out){
  int b = blockIdx.x, t = threadIdx.x, lane = t & 63, w = t >> 6;
  __shared__ float sSc[NBPB];
  __shared__ __align__(16) float sU[HDIM];
  __shared__ float sMD0;

  if (w == 0){
    float m = (lane < NBPB) ? pm[b*NBPB + lane] : -3.0e38f;
    float mx = m;
    mx = fmaxf(mx, __shfl_xor(mx, 1));  mx = fmaxf(mx, __shfl_xor(mx, 2));
    mx = fmaxf(mx, __shfl_xor(mx, 4));  mx = fmaxf(mx, __shfl_xor(mx, 8));
    mx = fmaxf(mx, __shfl_xor(mx, 16)); mx = fmaxf(mx, __shfl_xor(mx, 32));
    float sc = (lane < NBPB) ? __expf(m - mx) : 0.f;
    float d = sc * ((lane < NBPB) ? pd[b*NBPB + lane] : 0.f);
    d += __shfl_xor(d, 1); d += __shfl_xor(d, 2); d += __shfl_xor(d, 4);
    d += __shfl_xor(d, 8); d += __shfl_xor(d, 16); d += __shfl_xor(d, 32);
    if (lane < NBPB) sSc[lane] = sc;
    if (lane == 0) sMD0 = d;
  }
  __syncthreads();

  float inv = 1.f / sMD0;
  float u0 = 0.f, u1 = 0.f;
  #pragma unroll
  for (int c = 0; c < NBPB; ++c){
    float sc = sSc[c];
    const float* p = pu + ((size_t)(b*NBPB + c))*HDIM;
    u0 += sc * p[t];
    u1 += sc * p[t+256];
  }
  sU[t]     = u0 * inv;
  sU[t+256] = u1 * inv;
  __syncthreads();

  const f32x4* su4 = (const f32x4*)sU;
  for (int hh = 0; hh < 2; ++hh){
    int h = t + hh*256;
    const f32x4* w4 = (const f32x4*)(Wr + (size_t)h*HDIM);
    float acc = br[h];
    #pragma unroll 4
    for (int k = 0; k < HDIM/4; ++k){
      f32x4 wv = w4[k], uv = su4[k];
      acc += wv.x*uv.x + wv.y*uv.y + wv.z*uv.z + wv.w*uv.w;
    }
    out[b*HDIM + h] = acc;
  }
}

extern "C" void kernel_launch(void* const* d_in, const int* in_sizes, int n_in,
                              void* d_out, int out_size, void* d_ws, size_t ws_size,
                              hipStream_t stream){
  const float* query = (const float*)d_in[0];
  const float* ref   = (const float*)d_in[1];
  const float* Wq    = (const float*)d_in[2];
  const float* bq    = (const float*)d_in[3];
  const float* Wr    = (const float*)d_in[4];
  const float* br    = (const float*)d_in[5];
  const float* V     = (const float*)d_in[6];
  char* ws = (char*)d_ws;
  float*          qbv = (float*)(ws + WS_QB);
  unsigned short* wrb = (unsigned short*)(ws + WS_WRB);
  float*          pm  = (float*)(ws + WS_PM);
  float*          pd  = (float*)(ws + WS_PD);
  float*          pu  = (float*)(ws + WS_PU);
  float* out = (float*)d_out;

  k_prep<<<dim3(288), dim3(256), 0, stream>>>(Wr, wrb, query, Wq, bq, br, qbv);
  k_main<<<dim3(NBLK), dim3(1024), 0, stream>>>(ref, wrb, qbv, V, pm, pd, pu);
  k_final<<<dim3(BB), dim3(256), 0, stream>>>(Wr, br, pm, pd, pu, out);
}

// Round 6
// 195.289 us; speedup vs baseline: 2.3188x; 1.3761x over previous
//
#include <hip/hip_runtime.h>
#include <hip/hip_bf16.h>

// Sizes (fixed by the problem)
#define HDIM 512
#define BB 32
#define SS 4096
#define TR 32                  // rows per tile/block
#define NCH (SS/TR)            // 128 chunks per b
#define NBLK (BB*NCH)          // 4096 blocks

typedef __attribute__((ext_vector_type(8))) short short8;   // 8 x bf16
typedef __attribute__((ext_vector_type(4))) float f32x4;

// Workspace layout (bytes)
#define WS_QB    0                        // 32*512*4 = 65536
#define WS_WRBF  65536                    // 512*512*2 = 524288 (fragment-major)
#define WS_PM    (65536+524288)           // 4096*4 (16KB region)
#define WS_PD    (WS_PM+16384)            // 4096*4 (16KB region)
#define WS_PU    (WS_PD+16384)            // 4096*512*4 = 8MB

__device__ __forceinline__ unsigned short f2bf(float f){
  unsigned u = __float_as_uint(f);
  u += 0x7FFFu + ((u >> 16) & 1u);        // RNE
  return (unsigned short)(u >> 16);
}

__device__ __forceinline__ float fast_tanh(float x){
  float e = __expf(2.f * x);
  return 1.f - __fdividef(2.f, 1.f + e);
}

// ---------------- K1: prep (fused) ----------------
// blocks 0..127 : build fragment-major bf16 Wr:
//   wrbF[((t16*16 + kt)*64 + lane)*8 ..] = Wr[t16*16 + (lane&15)][kt*32 + (lane>>4)*8 ..+8]
//   -> k_main's B-fragment load for (t16,kt) is ONE contiguous 1KB wave load.
// blocks 128..159: qb[b,h] = bq[h] + br[h] + query[b,:] . Wq[h,:]
__global__ __launch_bounds__(256) void k_prep(const float* __restrict__ Wr,
                                              unsigned short* __restrict__ wrbF,
                                              const float* __restrict__ query,
                                              const float* __restrict__ Wq,
                                              const float* __restrict__ bq,
                                              const float* __restrict__ br,
                                              float* __restrict__ qb){
  int t = threadIdx.x;
  if (blockIdx.x < 128){
    int gid = blockIdx.x*256 + t;        // [0, 32768) : one 16B fragment chunk
    int lane = gid & 63;
    int tile = gid >> 6;                 // [0,512): kt = tile&15, t16 = tile>>4
    int kt = tile & 15, t16 = tile >> 4;
    int col = t16*16 + (lane & 15);
    int k0  = kt*32 + (lane >> 4)*8;
    const float* src = Wr + (size_t)col*HDIM + k0;
    f32x4 v0 = *(const f32x4*)(src);
    f32x4 v1 = *(const f32x4*)(src + 4);
    ushort4 o0, o1;
    o0.x = f2bf(v0.x); o0.y = f2bf(v0.y); o0.z = f2bf(v0.z); o0.w = f2bf(v0.w);
    o1.x = f2bf(v1.x); o1.y = f2bf(v1.y); o1.z = f2bf(v1.z); o1.w = f2bf(v1.w);
    ushort* dst = wrbF + (size_t)gid*8;
    *(ushort4*)(dst)     = o0;
    *(ushort4*)(dst + 4) = o1;
  } else {
    __shared__ __align__(16) float sq[HDIM];
    int b = blockIdx.x - 128;
    sq[t] = query[b*HDIM + t];
    sq[t+256] = query[b*HDIM + t + 256];
    __syncthreads();
    const f32x4* sq4 = (const f32x4*)sq;
    for (int hh = 0; hh < 2; ++hh){
      int h = t + hh*256;
      const f32x4* w4 = (const f32x4*)(Wq + (size_t)h*HDIM);
      float acc = bq[h] + br[h];
      #pragma unroll 4
      for (int k = 0; k < HDIM/4; ++k){
        f32x4 w = w4[k]; f32x4 q = sq4[k];
        acc += w.x*q.x + w.y*q.y + w.z*q.z + w.w*q.w;
      }
      qb[b*HDIM + h] = acc;
    }
  }
}

// ---------------- K2: main fused kernel ----------------
// 4096 blocks x 256 thr (4 waves), 32-row tile, ~37.5KB LDS -> 4 blocks/CU.
// Inter-block desync hides HBM/L2 latency (no lockstep barriers across CU).
// Per block: stage 32x512 f32 -> bf16 swizzled LDS (16 f32x4/thread in flight),
// GEMM vs fragment-major Wr (coalesced 1KB B-loads), tanh/V logits, chunk
// softmax, u-partial. Partials merged in k_final.
__global__ __launch_bounds__(256, 4) void k_main(const float* __restrict__ ref,
                                                 const unsigned short* __restrict__ wrbF,
                                                 const float* __restrict__ qb,
                                                 const float* __restrict__ V,
                                                 float* __restrict__ pm,
                                                 float* __restrict__ pd,
                                                 float* __restrict__ pu){
  int bid = blockIdx.x;
  int b = bid >> 7;
  int chunk = bid & 127;
  int tid = threadIdx.x;
  int w = tid >> 6, lane = tid & 63;
  int lo16 = lane & 15, g = lane >> 4;

  __shared__ __align__(16) unsigned short sA[TR*HDIM]; // 32KB swizzled bf16
  __shared__ __align__(16) float sQb[HDIM];
  __shared__ __align__(16) float sV[HDIM];
  __shared__ float sLog[4][TR];
  __shared__ float sE[TR];
  __shared__ float sMD[2];

  for (int i = tid; i < HDIM; i += 256){
    sQb[i] = qb[b*HDIM + i];
    sV[i]  = V[i];
  }

  // ---- stage A: 32 rows x 512 f32 = 4096 f32x4; 16 per thread, all in flight ----
  {
    const f32x4* s4 = (const f32x4*)(ref + ((size_t)b*SS + (size_t)chunk*TR)*HDIM) + tid;
    f32x4 R[16];
    #pragma unroll
    for (int i = 0; i < 16; ++i) R[i] = s4[256*i];
    #pragma unroll
    for (int i = 0; i < 16; ++i){
      int idx = tid + 256*i;
      int row = idx >> 7, c4 = idx & 127;
      f32x4 v = R[i];
      ushort4 o;
      o.x = f2bf(v.x); o.y = f2bf(v.y); o.z = f2bf(v.z); o.w = f2bf(v.w);
      unsigned byte = ((unsigned)(row*1024 + c4*8)) ^ ((unsigned)(row & 7) << 4);
      *(ushort4*)((char*)sA + byte) = o;
    }
  }
  __syncthreads();

  // ---- GEMM + logits: wave covers cols [w*128, w*128+128), rows 0..31 ----
  float lacc[2][4];
  #pragma unroll
  for (int m = 0; m < 2; ++m)
    #pragma unroll
    for (int r = 0; r < 4; ++r)
      lacc[m][r] = 0.f;

  #pragma unroll
  for (int nh = 0; nh < 2; ++nh){
    int tbase = w*8 + nh*4;             // t16 index for n=0..3
    f32x4 acc[2][4];
    #pragma unroll
    for (int m = 0; m < 2; ++m)
      #pragma unroll
      for (int n = 0; n < 4; ++n)
        acc[m][n] = (f32x4){0.f, 0.f, 0.f, 0.f};

    #pragma unroll 4
    for (int kt = 0; kt < 16; ++kt){
      short8 af[2];
      #pragma unroll
      for (int m = 0; m < 2; ++m){
        int row = 16*m + lo16;
        unsigned byte = ((unsigned)(row*1024 + kt*64 + g*16)) ^ ((unsigned)(row & 7) << 4);
        af[m] = *(const short8*)((const char*)sA + byte);
      }
      short8 bfr[4];
      #pragma unroll
      for (int n = 0; n < 4; ++n)
        bfr[n] = ((const short8*)wrbF)[ (size_t)((tbase + n)*16 + kt)*64 + lane ];
      #pragma unroll
      for (int m = 0; m < 2; ++m)
        #pragma unroll
        for (int n = 0; n < 4; ++n)
          acc[m][n] = __builtin_amdgcn_mfma_f32_16x16x32_bf16(af[m], bfr[n], acc[m][n], 0, 0, 0);
    }

    // epilogue: D-layout col=lane&15, row=16m+4g+r
    #pragma unroll
    for (int n = 0; n < 4; ++n){
      int col = (tbase + n)*16 + lo16;
      float qv = sQb[col], vv = sV[col];
      #pragma unroll
      for (int m = 0; m < 2; ++m)
        #pragma unroll
        for (int r = 0; r < 4; ++r){
          float x = qv + acc[m][n][r];
          lacc[m][r] += vv * fast_tanh(x);
        }
    }
  }

  // reduce over 16 lanes (cols) -> logits
  #pragma unroll
  for (int m = 0; m < 2; ++m)
    #pragma unroll
    for (int r = 0; r < 4; ++r){
      float v = lacc[m][r];
      v += __shfl_xor(v, 1); v += __shfl_xor(v, 2);
      v += __shfl_xor(v, 4); v += __shfl_xor(v, 8);
      lacc[m][r] = v;
    }
  if (lo16 == 0){
    #pragma unroll
    for (int m = 0; m < 2; ++m)
      #pragma unroll
      for (int r = 0; r < 4; ++r)
        sLog[w][16*m + 4*g + r] = lacc[m][r];
  }
  __syncthreads();

  // ---- chunk softmax partials (wave 0, lanes 0..31) ----
  if (w == 0){
    float l = (lane < TR)
      ? (sLog[0][lane] + sLog[1][lane] + sLog[2][lane] + sLog[3][lane])
      : -3.0e38f;
    float mx = l;
    mx = fmaxf(mx, __shfl_xor(mx, 1));  mx = fmaxf(mx, __shfl_xor(mx, 2));
    mx = fmaxf(mx, __shfl_xor(mx, 4));  mx = fmaxf(mx, __shfl_xor(mx, 8));
    mx = fmaxf(mx, __shfl_xor(mx, 16));
    float e = (lane < TR) ? __expf(l - mx) : 0.f;
    float d = e;
    d += __shfl_xor(d, 1); d += __shfl_xor(d, 2); d += __shfl_xor(d, 4);
    d += __shfl_xor(d, 8); d += __shfl_xor(d, 16);
    if (lane < TR) sE[lane] = e;
    if (lane == 0){ sMD[0] = mx; sMD[1] = d; }
  }
  __syncthreads();

  // ---- u[k] = sum_s e_s * A[s,k]  (k = 2*tid, 2*tid+1) ----
  float u0 = 0.f, u1 = 0.f;
  #pragma unroll 8
  for (int s = 0; s < TR; ++s){
    unsigned byte = ((unsigned)(s*1024 + tid*4)) ^ ((unsigned)(s & 7) << 4);
    unsigned pk = *(const unsigned*)((const char*)sA + byte);
    float e = sE[s];
    u0 += e * __uint_as_float((pk & 0xFFFFu) << 16);
    u1 += e * __uint_as_float(pk & 0xFFFF0000u);
  }
  pu[(size_t)bid*HDIM + 2*tid]     = u0;
  pu[(size_t)bid*HDIM + 2*tid + 1] = u1;
  if (tid == 0){ pm[bid] = sMD[0]; pd[bid] = sMD[1]; }
}

// ---------------- K3: combine 128 partials per b + out = Wr @ u + br ----------------
__global__ __launch_bounds__(256) void k_final(const float* __restrict__ Wr,
                                               const float* __restrict__ br,
                                               const float* __restrict__ pm,
                                               const float* __restrict__ pd,
                                               const float* __restrict__ pu,
                                               float* __restrict__ out){
  int b = blockIdx.x, t = threadIdx.x;
  __shared__ float sM[NCH], sD[NCH], sSc[NCH];
  __shared__ __align__(16) float sU[HDIM];
  __shared__ float sMx, sDen;

  if (t < NCH){ sM[t] = pm[b*NCH + t]; sD[t] = pd[b*NCH + t]; }
  __syncthreads();
  if (t < 64){
    float mx = fmaxf(sM[t], sM[t+64]);
    mx = fmaxf(mx, __shfl_xor(mx, 1));  mx = fmaxf(mx, __shfl_xor(mx, 2));
    mx = fmaxf(mx, __shfl_xor(mx, 4));  mx = fmaxf(mx, __shfl_xor(mx, 8));
    mx = fmaxf(mx, __shfl_xor(mx, 16)); mx = fmaxf(mx, __shfl_xor(mx, 32));
    if (t == 0) sMx = mx;
  }
  __syncthreads();
  float mx = sMx;
  if (t < NCH) sSc[t] = __expf(sM[t] - mx);
  __syncthreads();
  if (t < 64){
    float d = sSc[t]*sD[t] + sSc[t+64]*sD[t+64];
    d += __shfl_xor(d, 1); d += __shfl_xor(d, 2); d += __shfl_xor(d, 4);
    d += __shfl_xor(d, 8); d += __shfl_xor(d, 16); d += __shfl_xor(d, 32);
    if (t == 0) sDen = d;
  }
  __syncthreads();

  float inv = 1.f / sDen;
  float u0 = 0.f, u1 = 0.f;
  for (int c = 0; c < NCH; ++c){
    float sc = sSc[c];
    const float* p = pu + ((size_t)(b*NCH + c))*HDIM;
    u0 += sc * p[t];
    u1 += sc * p[t+256];
  }
  sU[t]     = u0 * inv;
  sU[t+256] = u1 * inv;
  __syncthreads();

  const f32x4* su4 = (const f32x4*)sU;
  for (int hh = 0; hh < 2; ++hh){
    int h = t + hh*256;
    const f32x4* w4 = (const f32x4*)(Wr + (size_t)h*HDIM);
    float acc = br[h];
    #pragma unroll 4
    for (int k = 0; k < HDIM/4; ++k){
      f32x4 wv = w4[k], uv = su4[k];
      acc += wv.x*uv.x + wv.y*uv.y + wv.z*uv.z + wv.w*uv.w;
    }
    out[b*HDIM + h] = acc;
  }
}

extern "C" void kernel_launch(void* const* d_in, const int* in_sizes, int n_in,
                              void* d_out, int out_size, void* d_ws, size_t ws_size,
                              hipStream_t stream){
  const float* query = (const float*)d_in[0];
  const float* ref   = (const float*)d_in[1];
  const float* Wq    = (const float*)d_in[2];
  const float* bq    = (const float*)d_in[3];
  const float* Wr    = (const float*)d_in[4];
  const float* br    = (const float*)d_in[5];
  const float* V     = (const float*)d_in[6];
  char* ws = (char*)d_ws;
  float*          qbv  = (float*)(ws + WS_QB);
  unsigned short* wrbF = (unsigned short*)(ws + WS_WRBF);
  float*          pm   = (float*)(ws + WS_PM);
  float*          pd   = (float*)(ws + WS_PD);
  float*          pu   = (float*)(ws + WS_PU);
  float* out = (float*)d_out;

  k_prep<<<dim3(160), dim3(256), 0, stream>>>(Wr, wrbF, query, Wq, bq, br, qbv);
  k_main<<<dim3(NBLK), dim3(256), 0, stream>>>(ref, wrbF, qbv, V, pm, pd, pu);
  k_final<<<dim3(BB), dim3(256), 0, stream>>>(Wr, br, pm, pd, pu, out);
}